// Round 5
// baseline (62.679 us; speedup 1.0000x reference)
//
#include <hip/hip_runtime.h>

// YOLO-style loss, B=131072, GRID=7, CELLS=49, 11 floats/cell.
// outputs: (B,539) fp32 -> linear stream of 11-float cells (cell g at float 11g).
// target:  (B,2,4) fp32.
// R2: non-atomic partial-store reduction. 77us.
// R3: CPC=512 (22.5KB LDS, 7 blocks/CU, 28 waves/CU). 58us.
// R4: persistent blocks (1792 x 7 chunks) + register-prefetch pipeline:
//     per iter {ds_write prefetched regs; barrier; prefetch next chunk to
//     regs; compute current from LDS}. Loads stay in flight across chunk
//     boundaries instead of draining at 12544 block boundaries.

constexpr int BLOCK = 256;
constexpr int CPC = 512;                        // cells per chunk
constexpr int FLOATS_PER_CHUNK = CPC * 11;      // 5632
constexpr int F4C = FLOATS_PER_CHUNK / 4;       // 1408 = 5.5 * 256
constexpr int TOTAL_CELLS = 131072 * 49;        // 6422528
constexpr int NCHUNKS = TOTAL_CELLS / CPC;      // 12544
constexpr int GRIDSZ = 1792;                    // 7 blocks/CU * 256 CU
constexpr int CPB = NCHUNKS / GRIDSZ;           // 7 chunks per block (exact)

__global__ __launch_bounds__(BLOCK, 7) void yolo_loss_kernel(
    const float* __restrict__ outputs,
    const float* __restrict__ target,
    double* __restrict__ part)
{
#pragma clang fp contract(off)
    __shared__ float lds[FLOATS_PER_CHUNK];     // 22528 B
    __shared__ double wred[BLOCK / 64];

    const int t = threadIdx.x;
    const float4* srcb = reinterpret_cast<const float4*>(outputs);
    const float4* tg4 = reinterpret_cast<const float4*>(target);
    float4* l4 = reinterpret_cast<float4*>(lds);
    const float CW = 1.0f / 7.0f;

    double a = 0.0;
    unsigned chunk = blockIdx.x;

    // prologue: load chunk 0 into regs
    float4 r0, r1, r2, r3, r4, r5;
    r5 = make_float4(0.f, 0.f, 0.f, 0.f);
    {
        const float4* s = srcb + (size_t)chunk * F4C;
        r0 = s[t];        r1 = s[t + 256];  r2 = s[t + 512];
        r3 = s[t + 768];  r4 = s[t + 1024];
        if (t < 128) r5 = s[t + 1280];      // wave-aligned half round
    }

    for (int k = 0; k < CPB; ++k) {
        __syncthreads();                     // all waves done reading LDS
        // commit prefetched regs to LDS (vmcnt wait via data dep)
        l4[t] = r0;          l4[t + 256] = r1;  l4[t + 512] = r2;
        l4[t + 768] = r3;    l4[t + 1024] = r4;
        if (t < 128) l4[t + 1280] = r5;
        __syncthreads();

        // issue next chunk's loads BEFORE compute (latency hides under it)
        const unsigned next = chunk + GRIDSZ;
        if (k < CPB - 1) {
            const float4* s = srcb + (size_t)next * F4C;
            r0 = s[t];        r1 = s[t + 256];  r2 = s[t + 512];
            r3 = s[t + 768];  r4 = s[t + 1024];
            if (t < 128) r5 = s[t + 1280];
        }

        // ---- compute current chunk (2 cells/thread)
#pragma unroll
        for (int q = 0; q < 2; ++q) {
            const int cl = t + BLOCK * q;
            const unsigned g = chunk * CPC + cl;
            const unsigned b = g / 49u;
            const unsigned s = g - b * 49u;
            const float xl = (float)(s % 7u) / 7.0f;   // exact fp32 div
            const float yl = (float)(s / 7u) / 7.0f;

            const float4 T0 = tg4[2u * b];
            const float4 T1 = tg4[2u * b + 1u];
            const bool v1 = (T1.x != -1.0f);

            const float* cp = lds + cl * 11;           // 11t: coprime w/ 32 banks

            float conf0, conf1, term0, term1;
            bool one0, one1;
            {   // box j=0 (always valid)
                const float px = cp[0], py = cp[1], pw = cp[2], ph = cp[3], pc = cp[4];
                const float tx = T0.x, ty = T0.y, tw = T0.z, th = T0.w;
                const float ix = fabsf(fmaxf(px - 0.5f * pw, tx - 0.5f * tw)
                                     - fminf(px + 0.5f * pw, tx + 0.5f * tw));
                const float iy = fabsf(fmaxf(py - 0.5f * ph, ty - 0.5f * th)
                                     - fminf(py + 0.5f * ph, ty + 0.5f * th));
                const float inter = ix * iy;
                const float uni = pw * ph + tw * th - inter;
                conf0 = inter / uni;
                one0 = (xl <= tx) && (tx <= xl + CW) && (yl <= ty) && (ty <= yl + CW);
                const float d0 = tx - px, d1 = ty - py;
                const float d2 = sqrtf(tw) - sqrtf(pw);
                const float d3 = sqrtf(th) - sqrtf(ph);
                const float coord = ((d0 * d0 + d1 * d1) + d2 * d2) + d3 * d3;
                const float dc = conf0 - pc;
                term0 = one0 ? (5.0f * coord + dc * dc) : (0.5f * pc * pc);
            }
            {   // box j=1 (valid iff T1.x != -1)
                const float px = cp[5], py = cp[6], pw = cp[7], ph = cp[8], pc = cp[9];
                const float tx = T1.x, ty = T1.y, tw = T1.z, th = T1.w;
                const float ix = fabsf(fmaxf(px - 0.5f * pw, tx - 0.5f * tw)
                                     - fminf(px + 0.5f * pw, tx + 0.5f * tw));
                const float iy = fabsf(fmaxf(py - 0.5f * ph, ty - 0.5f * th)
                                     - fminf(py + 0.5f * ph, ty + 0.5f * th));
                const float inter = ix * iy;
                const float uni = pw * ph + tw * th - inter;
                conf1 = inter / uni;
                const bool inx = (xl <= tx) && (tx <= xl + CW);
                const bool iny = (yl <= ty) && (ty <= yl + CW);
                one1 = inx && iny && v1;
                const float d0 = tx - px, d1 = ty - py;
                const float d2 = sqrtf(tw) - sqrtf(pw);
                const float d3 = sqrtf(th) - sqrtf(ph);
                const float coord = ((d0 * d0 + d1 * d1) + d2 * d2) + d3 * d3;
                const float dc = conf1 - pc;
                term1 = one1 ? (5.0f * coord + dc * dc)
                             : (v1 ? (0.5f * pc * pc) : 0.0f);
            }
            const float sum_conf = conf0 + (v1 ? conf1 : 0.0f);
            float cls = 0.0f;
            if (one0 || one1) {
                const float d = cp[10] - sum_conf;
                cls = d * d;
            }
            a += (double)term0 + (double)term1 + (double)cls;
        }
        chunk = next;
    }

    // ---- reduction: wave shfl -> LDS -> block partial -> d_ws (NO atomics)
#pragma unroll
    for (int off = 32; off > 0; off >>= 1)
        a += __shfl_down(a, off);
    if ((t & 63) == 0) wred[t >> 6] = a;
    __syncthreads();
    if (t == 0)
        part[blockIdx.x] = wred[0] + wred[1] + wred[2] + wred[3];
}

constexpr int RBLOCK = 1024;
__global__ __launch_bounds__(RBLOCK) void reduce_kernel(
    const double* __restrict__ part, float* __restrict__ out)
{
    __shared__ double wred[RBLOCK / 64];
    const int t = threadIdx.x;
    double a = 0.0;
    for (int i = t; i < GRIDSZ; i += RBLOCK)
        a += part[i];
#pragma unroll
    for (int off = 32; off > 0; off >>= 1)
        a += __shfl_down(a, off);
    if ((t & 63) == 0) wred[t >> 6] = a;
    __syncthreads();
    if (t == 0) {
        double s = 0.0;
#pragma unroll
        for (int i = 0; i < RBLOCK / 64; ++i) s += wred[i];
        out[0] = (float)s;
    }
}

extern "C" void kernel_launch(void* const* d_in, const int* in_sizes, int n_in,
                              void* d_out, int out_size, void* d_ws, size_t ws_size,
                              hipStream_t stream)
{
    const float* outputs = (const float*)d_in[0];
    const float* target  = (const float*)d_in[1];
    float* out = (float*)d_out;
    double* part = (double*)d_ws;   // GRIDSZ doubles = 14336 B

    yolo_loss_kernel<<<GRIDSZ, BLOCK, 0, stream>>>(outputs, target, part);
    reduce_kernel<<<1, RBLOCK, 0, stream>>>(part, out);
}

// Round 6
// 59.489 us; speedup vs baseline: 1.0536x; 1.0536x over previous
//
#include <hip/hip_runtime.h>

// YOLO-style loss, B=131072, GRID=7, CELLS=49, 11 floats/cell.
// R2: non-atomic partial reduction. 77us. R3: CPC=512 occupancy. 58us.
// R4: persistent pipeline REGRESSED (62us) - TLP across short blocks was
//     already hiding latency; reverted.
// R5: algebraic restructure. one_j depends only on (target, cell idx), and
//     ~96% of cells need only 0.5*pc^2 (2 of 11 floats, no div/sqrt/IoU).
//     total = SUM_valid 0.5*pc^2          (bulk role: streaming, ~12 VALU/cell)
//           + SUM_one-cells [(obj-noobj)+cls]  (heavy role: 1 thread/sample,
//             exact candidate search + 44B gather + bit-exact IEEE math)
//     Kills the ~50us VALU wall (div/sqrt/IoU per cell) measured via
//     VALUBusy*dur in R1's profile.

constexpr int BLOCK = 256;
constexpr int B_SAMPLES = 131072;
constexpr int TOTAL_CELLS = B_SAMPLES * 49;     // 6422528
constexpr int BULK_BLOCKS = 2048;               // 8 blocks/CU, pure streaming
constexpr int HEAVY_BLOCKS = B_SAMPLES / BLOCK; // 512 (1 thread per sample)
constexpr int GRID_TOTAL = BULK_BLOCKS + HEAVY_BLOCKS;  // 2560
constexpr int BULK_THREADS = BULK_BLOCKS * BLOCK;       // 524288

__device__ __forceinline__ double block_reduce_f64(double a, double* wred, int t)
{
#pragma unroll
    for (int off = 32; off > 0; off >>= 1)
        a += __shfl_down(a, off);
    if ((t & 63) == 0) wred[t >> 6] = a;
    __syncthreads();
    double s = 0.0;
    if (t == 0) {
#pragma unroll
        for (int i = 0; i < BLOCK / 64; ++i) s += wred[i];
    }
    return s;
}

// exact replication of ref's in-cell test: (i/7f <= tx) && (tx <= i/7f + CW).
// satisfying i form a contiguous range within [floor(7tx)-1, floor(7tx)+1].
__device__ __forceinline__ int cands(float tx, int* out)
{
    int ig = (int)(tx * 7.0f);
    if (ig < 0) ig = 0;
    if (ig > 6) ig = 6;
    int lo = ig - 1; if (lo < 0) lo = 0;
    int hi = ig + 1; if (hi > 6) hi = 6;
    int n = 0;
    for (int i = lo; i <= hi; ++i) {
        const float xl = (float)i / 7.0f;          // IEEE div == numpy
        const float xh = xl + (1.0f / 7.0f);       // fl(xl + fl(1/7)) == numpy
        if (xl <= tx && tx <= xh) out[n++] = i;
    }
    return n;
}

__device__ __forceinline__ float iou_f(float px, float py, float pw, float ph,
                                       float tx, float ty, float tw, float th)
{
#pragma clang fp contract(off)
    const float ix = fabsf(fmaxf(px - 0.5f * pw, tx - 0.5f * tw)
                         - fminf(px + 0.5f * pw, tx + 0.5f * tw));
    const float iy = fabsf(fmaxf(py - 0.5f * ph, ty - 0.5f * th)
                         - fminf(py + 0.5f * ph, ty + 0.5f * th));
    const float inter = ix * iy;
    const float uni = pw * ph + tw * th - inter;
    return inter / uni;                             // IEEE div == numpy
}

// correction for one one-cell: [one0 ? obj0-noobj0] + [one1 ? obj1-noobj1] + cls
__device__ __forceinline__ double proc_cell(const float* __restrict__ outputs,
                                            unsigned g, float4 T0, float4 T1,
                                            bool v1, bool o0, bool o1)
{
#pragma clang fp contract(off)
    const float* cp = outputs + 11u * (size_t)g;    // 4B-aligned: scalar loads
    const float f0 = cp[0], f1 = cp[1], f2 = cp[2], f3 = cp[3], f4 = cp[4];
    const float f5 = cp[5], f6 = cp[6], f7 = cp[7], f8 = cp[8], f9 = cp[9];
    const float f10 = cp[10];

    const float conf0 = iou_f(f0, f1, f2, f3, T0.x, T0.y, T0.z, T0.w);
    const float conf1 = iou_f(f5, f6, f7, f8, T1.x, T1.y, T1.z, T1.w);

    double corr = 0.0;
    if (o0) {
        const float d0 = T0.x - f0, d1 = T0.y - f1;
        const float d2 = sqrtf(T0.z) - sqrtf(f2);
        const float d3 = sqrtf(T0.w) - sqrtf(f3);
        const float coord = ((d0 * d0 + d1 * d1) + d2 * d2) + d3 * d3;
        const float dc = conf0 - f4;
        const float obj = 5.0f * coord + dc * dc;
        const float noobj = 0.5f * (f4 * f4);
        corr += (double)obj - (double)noobj;
    }
    if (o1) {
        const float d0 = T1.x - f5, d1 = T1.y - f6;
        const float d2 = sqrtf(T1.z) - sqrtf(f7);
        const float d3 = sqrtf(T1.w) - sqrtf(f8);
        const float coord = ((d0 * d0 + d1 * d1) + d2 * d2) + d3 * d3;
        const float dc = conf1 - f9;
        const float obj = 5.0f * coord + dc * dc;
        const float noobj = 0.5f * (f9 * f9);
        corr += (double)obj - (double)noobj;
    }
    // cls: this is a one_i cell by construction
    const float sum_conf = conf0 + (v1 ? conf1 : 0.0f);
    const float dcls = f10 - sum_conf;
    corr += (double)(dcls * dcls);
    return corr;
}

__global__ __launch_bounds__(BLOCK) void yolo_loss_kernel(
    const float* __restrict__ outputs,
    const float* __restrict__ target,
    double* __restrict__ part)
{
    __shared__ double wred[BLOCK / 64];
    const int t = threadIdx.x;
    const unsigned blk = blockIdx.x;
    double a = 0.0;

    if (blk < BULK_BLOCKS) {
        // ---- bulk role: SUM over all cells of pc0^2 + (v1 ? pc1^2 : 0)
        const unsigned tid = blk * BLOCK + t;
        float sumf = 0.0f;
        for (unsigned g = tid; g < (unsigned)TOTAL_CELLS; g += BULK_THREADS) {
            const unsigned b = g / 49u;
            const float pc0 = outputs[11u * (size_t)g + 4u];
            const float pc1 = outputs[11u * (size_t)g + 9u];
            const float t1x = target[8u * (size_t)b + 4u];
            float s2 = pc0 * pc0;
            if (t1x != -1.0f) s2 += pc1 * pc1;
            sumf += s2;
        }
        a = 0.5 * (double)sumf;
    } else {
        // ---- heavy role: one thread per sample; exact one-cell corrections
        const unsigned b = (blk - BULK_BLOCKS) * BLOCK + t;
        const float4* tg4 = reinterpret_cast<const float4*>(target);
        const float4 T0 = tg4[2u * b];
        const float4 T1 = tg4[2u * b + 1u];
        const bool v1 = (T1.x != -1.0f);

        int cx0[3], cy0[3], cx1[3], cy1[3];
        int nx0 = cands(T0.x, cx0);
        int ny0 = cands(T0.y, cy0);
        int nx1 = 0, ny1 = 0;
        if (v1) { nx1 = cands(T1.x, cx1); ny1 = cands(T1.y, cy1); }

        const unsigned base = 49u * b;
        // cells where one0 (may also be one1)
        for (int ai = 0; ai < nx0; ++ai)
            for (int bi = 0; bi < ny0; ++bi) {
                const int s = cy0[bi] * 7 + cx0[ai];
                bool o1 = false;
                for (int ci = 0; ci < nx1; ++ci)
                    for (int di = 0; di < ny1; ++di)
                        if (cy1[di] * 7 + cx1[ci] == s) o1 = true;
                a += proc_cell(outputs, base + s, T0, T1, v1, true, o1);
            }
        // cells where one1 only
        for (int ci = 0; ci < nx1; ++ci)
            for (int di = 0; di < ny1; ++di) {
                const int s = cy1[di] * 7 + cx1[ci];
                bool o0 = false;
                for (int ai = 0; ai < nx0; ++ai)
                    for (int bi = 0; bi < ny0; ++bi)
                        if (cy0[bi] * 7 + cx0[ai] == s) o0 = true;
                if (!o0)
                    a += proc_cell(outputs, base + s, T0, T1, v1, false, true);
            }
    }

    const double s = block_reduce_f64(a, wred, t);
    if (t == 0) part[blk] = s;
}

constexpr int RBLOCK = 1024;
__global__ __launch_bounds__(RBLOCK) void reduce_kernel(
    const double* __restrict__ part, float* __restrict__ out)
{
    __shared__ double wred[RBLOCK / 64];
    const int t = threadIdx.x;
    double a = 0.0;
    for (int i = t; i < GRID_TOTAL; i += RBLOCK)
        a += part[i];
#pragma unroll
    for (int off = 32; off > 0; off >>= 1)
        a += __shfl_down(a, off);
    if ((t & 63) == 0) wred[t >> 6] = a;
    __syncthreads();
    if (t == 0) {
        double s = 0.0;
#pragma unroll
        for (int i = 0; i < RBLOCK / 64; ++i) s += wred[i];
        out[0] = (float)s;
    }
}

extern "C" void kernel_launch(void* const* d_in, const int* in_sizes, int n_in,
                              void* d_out, int out_size, void* d_ws, size_t ws_size,
                              hipStream_t stream)
{
    const float* outputs = (const float*)d_in[0];
    const float* target  = (const float*)d_in[1];
    float* out = (float*)d_out;
    double* part = (double*)d_ws;   // GRID_TOTAL doubles = 20480 B

    yolo_loss_kernel<<<GRID_TOTAL, BLOCK, 0, stream>>>(outputs, target, part);
    reduce_kernel<<<1, RBLOCK, 0, stream>>>(part, out);
}